// Round 1
// baseline (144.600 us; speedup 1.0000x reference)
//
#include <hip/hip_runtime.h>
#include <hip/hip_fp16.h>

// BackProjectionLinear: out[b,p] = sum_d apod[d] * lerp(sino[b,d], k[p,d], a[p,d]) / norm
// B=4, N_DET=128, N_T=2048, pixels=256*256=65536.
//
// Design: lut (64MB) is the HBM floor (~10us). sino (4MB) gathers are random
// in t -> must be served from LDS (8B/gather) not cache lines (64B/gather).
// Block = 8 detectors x 2048 pixels; sino rows staged to LDS as fp16
// (4 det x 4 batch x 2048 t x 2B = 64KB -> 2 blocks/CU), two staging phases
// per block so each pixel's lut read is one full 64B line. Partial sums over
// the block's 8 detectors go to d_out via atomicAdd (out zeroed by memset).

#define NB      4
#define NDET    128
#define NT      2048
#define NPIX    65536
#define DPHASE  4            // detectors staged per phase
#define DBLOCK  8            // detectors per block (2 phases)
#define PTILE   2048         // pixels per block
#define THREADS 512
#define PXPT    (PTILE / THREADS)   // 4 pixels per thread

__global__ __launch_bounds__(THREADS, 4)
void bp_kernel(const float* __restrict__ sino,
               const float* __restrict__ lut,
               float* __restrict__ out) {
    // LDS layout: [dl (0..3)][t (0..2047)][b (0..3)] as __half. 65536 bytes.
    __shared__ __half lds[DPHASE * NT * NB];

    const int tid  = threadIdx.x;
    const int pair = blockIdx.x & 15;   // 16 detector-octets
    const int tile = blockIdx.x >> 4;   // 32 pixel tiles
    const int d0   = pair * DBLOCK;
    const int px0  = tile * PTILE;

    // apod weights for this block's 8 detectors
    float apod[DBLOCK];
#pragma unroll
    for (int j = 0; j < DBLOCK; ++j) {
        float x = (float)(d0 + j) * (6.28318530717958647692f / 127.0f);
        apod[j] = 0.5f - 0.5f * __cosf(x);
    }

    float acc[PXPT][NB];
#pragma unroll
    for (int i = 0; i < PXPT; ++i)
#pragma unroll
        for (int b = 0; b < NB; ++b) acc[i][b] = 0.0f;

    const float4* sino4 = (const float4*)sino;

    for (int phase = 0; phase < 2; ++phase) {
        const int dg0 = d0 + phase * DPHASE;
        if (phase) __syncthreads();   // readers of phase 0 done before overwrite

        // ---- stage 4 det x 4 batch x 2048 t into LDS as fp16 ----
        // 8192 float4 loads, coalesced along t.
        for (int f = tid; f < DPHASE * NB * (NT / 4); f += THREADS) {
            int t4 = f & 511;          // float4 index along t
            int r  = f >> 9;           // 0..15
            int dl = r >> 2;
            int b  = r & 3;
            float4 v = sino4[((size_t)b * NDET + (dg0 + dl)) * (NT / 4) + t4];
            int t = t4 * 4;
            __half* dst = &lds[(dl * NT + t) * NB + b];
            dst[0 * NB] = __float2half(v.x);
            dst[1 * NB] = __float2half(v.y);
            dst[2 * NB] = __float2half(v.z);
            dst[3 * NB] = __float2half(v.w);
        }
        __syncthreads();

        // ---- accumulate this phase's 4 detectors for 4 pixels/thread ----
#pragma unroll
        for (int i = 0; i < PXPT; ++i) {
            const int px = px0 + tid + i * THREADS;
            // lut[px][dg0 .. dg0+3][{k,a}] : 32 contiguous bytes, 32B-aligned
            const float4* lp = (const float4*)(lut + ((size_t)px * NDET + dg0) * 2);
            float4 L0 = lp[0];   // (k,a) for dg0+0, dg0+1
            float4 L1 = lp[1];   // (k,a) for dg0+2, dg0+3

            auto do_det = [&](float kf, float af, int dl, int j) {
                int k = (int)kf;                       // trunc toward zero, matches astype(int32)
                unsigned uk = (unsigned)k;
                bool valid = uk < 2047u;               // covers k<0 via wraparound
                float w  = valid ? apod[j] : 0.0f;
                int  k0  = valid ? k : 0;
                const __half2* q = (const __half2*)&lds[(dl * NT + k0) * NB];
                __half2 s0a = q[0], s0b = q[1];        // t=k0,  b=0..3
                __half2 s1a = q[2], s1b = q[3];        // t=k0+1,b=0..3
                __half2 a2  = __float2half2_rn(af);
                __half2 ska = __hfma2(a2, __hsub2(s1a, s0a), s0a);
                __half2 skb = __hfma2(a2, __hsub2(s1b, s0b), s0b);
                float2 fa = __half22float2(ska);
                float2 fb = __half22float2(skb);
                acc[i][0] = fmaf(w, fa.x, acc[i][0]);
                acc[i][1] = fmaf(w, fa.y, acc[i][1]);
                acc[i][2] = fmaf(w, fb.x, acc[i][2]);
                acc[i][3] = fmaf(w, fb.y, acc[i][3]);
            };
            int jb = phase * DPHASE;
            do_det(L0.x, L0.y, 0, jb + 0);
            do_det(L0.z, L0.w, 1, jb + 1);
            do_det(L1.x, L1.y, 2, jb + 2);
            do_det(L1.z, L1.w, 3, jb + 3);
        }
    }

    // ---- emit partial sums (16 blocks contribute per output element) ----
    const float inv_norm = 1.0f / 63.5f;   // sum(apod) == 63.5 exactly
#pragma unroll
    for (int i = 0; i < PXPT; ++i) {
        const int px = px0 + tid + i * THREADS;
#pragma unroll
        for (int b = 0; b < NB; ++b) {
            atomicAdd(&out[(size_t)b * NPIX + px], acc[i][b] * inv_norm);
        }
    }
}

extern "C" void kernel_launch(void* const* d_in, const int* in_sizes, int n_in,
                              void* d_out, int out_size, void* d_ws, size_t ws_size,
                              hipStream_t stream) {
    const float* sino = (const float*)d_in[0];
    const float* lut  = (const float*)d_in[1];
    float* out = (float*)d_out;

    hipMemsetAsync(d_out, 0, (size_t)out_size * sizeof(float), stream);

    // grid: 16 detector-octets x 32 pixel tiles = 512 blocks (2/CU resident)
    bp_kernel<<<dim3(512), dim3(THREADS), 0, stream>>>(sino, lut, out);
}